// Round 1
// baseline (383.985 us; speedup 1.0000x reference)
//
#include <hip/hip_runtime.h>

#define TT 2048
#define NV 1000
#define LOG2E 1.4426950408889634f

// ---- XLA/Eigen rational tanh — epilogue head only (off critical path).
__device__ __forceinline__ float tanh_fast(float x) {
    const float L = 7.90531110763549805f;
    x = __builtin_amdgcn_fmed3f(x, -L, L);
    float x2 = x * x;
    float p = -2.76076847742355e-16f;
    p = __builtin_fmaf(p, x2, 2.00018790482477e-13f);
    p = __builtin_fmaf(p, x2, -8.60467152213735e-11f);
    p = __builtin_fmaf(p, x2, 5.12229709037114e-08f);
    p = __builtin_fmaf(p, x2, 1.48572235717979e-05f);
    p = __builtin_fmaf(p, x2, 6.37261928875436e-04f);
    p = __builtin_fmaf(p, x2, 4.89352455891786e-03f);
    float q = 1.19825839466702e-06f;
    q = __builtin_fmaf(q, x2, 1.18534705686654e-04f);
    q = __builtin_fmaf(q, x2, 2.26843463243900e-03f);
    q = __builtin_fmaf(q, x2, 4.89352518554385e-03f);
    float r = __builtin_amdgcn_rcpf(q);
    return (x * p) * r;
}

template <int CTRL>
__device__ __forceinline__ float dppf(float x) {
    return __int_as_float(__builtin_amdgcn_update_dpp(
        0, __float_as_int(x), CTRL, 0xF, 0xF, true));
}
#define DPP_QP1  0xB1   // quad_perm [1,0,3,2] == xor1 within quad
#define DPP_QP2  0x4E   // quad_perm [2,3,0,1] == xor2 within quad
#define DPP_QP3  0x1B   // quad_perm [3,2,1,0] == xor3 within quad
#define DPP_ROR4 0x124  // row_ror:4  (used only where src replicated in both
                        //  candidate quads -> correct under either direction)
#define DPP_ROR8 0x128  // row_ror:8 == exact xor8 within 16-lane row

// ds_swizzle BitMode xor16: lane i <- lane i^16 within each 32-lane group.
__device__ __forceinline__ float swz_xor16(float x) {
    return __int_as_float(__builtin_amdgcn_ds_swizzle(__float_as_int(x), 0x401F));
}

// R12: 32 lanes/row (was 16). 512-thread blocks, 256 blocks, 16 rows/block ->
// 8 waves/block = 2 waves/SIMD (was 1). Each lane owns ONE gate:
//   L = 16*hi + 4*q + jj ;  j = 4*hi + jj ;  q: 0=i 1=f 2=g 3=o
// Combos by construction:
//   ar = xor8(a):  q0<->q2 pairs sigma(i)<->tanh(g); q1<->q3 pairs F<->O.
//   P  = a*ar   :  IG at q0 AND q2 (replicated) -> ror4 direction-immune.
//   Pr = ror4(P):  IG lands at q1,q3 (where c lives) either direction.
//   hq = ror4(h):  h (valid at q1,q3) lands at q0,q2 either direction.
//   hswz = ds_swizzle xor16: h_{j^4} for dot terms m=4..7 (1 swizzle/step).
// All per-gate arithmetic (term order, clamps, exp-form sigma/tanh) is
// bitwise-identical to the validated 16-lane R11 kernel.
extern "C" __global__ void __launch_bounds__(512, 2)
lstm_fused(const int* __restrict__ x, const float* __restrict__ emb,
           const float* __restrict__ W_ih, const float* __restrict__ W_hh,
           const float* __restrict__ b_ih, const float* __restrict__ b_hh,
           const float* __restrict__ W_cls, const float* __restrict__ b_cls,
           float* __restrict__ out)
{
    extern __shared__ float TAB[];  // [1000][32] floats, 128 B row stride

    const int tid = threadIdx.x;
    const int L   = tid & 31;           // lane within row-group
    const int grp = tid >> 5;           // 16 row-groups per block
    const int q   = (L >> 2) & 3;       // gate type: 0 i, 1 f, 2 g, 3 o
    const int hi  = L >> 4;
    const int j   = (hi << 2) | (L & 3);
    const int grow = q * 8 + j;         // row in W_ih / W_hh / biases (ifgo)
    const bool isG  = (q == 2);
    const float sc  = isG ? (-2.0f * LOG2E) : -LOG2E;  // prescale
    const float kL  = isG ? 1.0f : 0.0f;               // numerator: n = 1-kL*e
    const bool isq1  = (q == 1);
    const bool isOdd = (q & 1);

    // ---- phase 1: build TAB (one gate pre-activation per lane) ----
    {
        float w[8];
        #pragma unroll
        for (int k = 0; k < 8; ++k) w[k] = W_ih[grow * 8 + k];
        const float bb = b_ih[grow] + b_hh[grow];
        for (int v = grp; v < NV; v += 16) {
            const float4 e0 = *(const float4*)(emb + v * 8);
            const float4 e1 = *(const float4*)(emb + v * 8 + 4);
            float d = bb + e0.x*w[0] + e0.y*w[1] + e0.z*w[2] + e0.w*w[3]
                         + e1.x*w[4] + e1.y*w[5] + e1.z*w[6] + e1.w*w[7];
            TAB[v * 32 + L] = sc * d;
        }
    }
    __syncthreads();

    // ---- recurrence ----
    const int b = blockIdx.x * 16 + grp;
    const int* __restrict__ xrow = x + (size_t)b * TT;
    const char* __restrict__ TABl = (const char*)TAB + L * 4;

    // xor-ordered W_hh: term m multiplies h_{j^m}
    float w[8];
    #pragma unroll
    for (int m = 0; m < 8; ++m)
        w[m] = sc * W_hh[grow * 8 + (j ^ m)];

    float c  = 0.0f;
    float hn = 0.0f;   // h_j broadcast to all 4 quads (period-4 per 16-row)

    int4 iA = *(const int4*)(xrow);
    int4 iB = *(const int4*)(xrow + 4);
    float xg0 = *(const float*)(TABl + (iA.x << 7));  // depth-2 prefetch
    float xg1 = *(const float*)(TABl + (iA.y << 7));

    // Dot chain order per accumulator == R11: uA: m0,m2,m4,m6; uB: m1,m3,m5,m7.
#define STEP(XG, NIDX) do {                                                    \
        float hs = swz_xor16(hn);               /* h_{j^4}, issued first */    \
        float uA = __builtin_fmaf(w[0], hn, XG);                               \
        float uB = dppf<DPP_QP1>(hn) * w[1];                                   \
        uA = __builtin_fmaf(dppf<DPP_QP2>(hn), w[2], uA);                      \
        uB = __builtin_fmaf(dppf<DPP_QP3>(hn), w[3], uB);                      \
        uA = __builtin_fmaf(hs, w[4], uA);                                     \
        uB = __builtin_fmaf(dppf<DPP_QP1>(hs), w[5], uB);                      \
        uA = __builtin_fmaf(dppf<DPP_QP2>(hs), w[6], uA);                      \
        uB = __builtin_fmaf(dppf<DPP_QP3>(hs), w[7], uB);                      \
        float u = uA + uB;                                                     \
        XG = *(const float*)(TABl + ((NIDX) << 7));   /* prefetch t+2 */       \
        float e  = __builtin_amdgcn_exp2f(fminf(u, 126.0f));                   \
        float nl = __builtin_fmaf(-kL, e, 1.0f);   /* sigma: 1; g: 1-e */      \
        float a  = nl * __builtin_amdgcn_rcpf(1.0f + e);                       \
        float ar = dppf<DPP_ROR8>(a);           /* xor8 partner */             \
        float P  = a * ar;                      /* IG at q0,q2 */              \
        float Pr = dppf<DPP_ROR4>(P);           /* IG -> q1,q3 */              \
        float Fv = isq1 ? a  : ar;              /* sigma(f) at q1,q3 */        \
        float Ov = isq1 ? ar : a;               /* sigma(o) at q1,q3 */        \
        c = __builtin_fmaf(Fv, c, Pr);                                         \
        float uc = fminf(c * (-2.0f * LOG2E), 126.0f);                         \
        float ec = __builtin_amdgcn_exp2f(uc);                                 \
        float tc = (1.0f - ec) * __builtin_amdgcn_rcpf(1.0f + ec);             \
        float h  = Ov * tc;                     /* h_j at q1,q3 */             \
        float hq = dppf<DPP_ROR4>(h);           /* h_j -> q0,q2 */             \
        hn = isOdd ? h : hq;                                                   \
    } while (0)

    for (int t = 0; t < TT; t += 4) {
        const int nb = (t + 8 < TT) ? (t / 4 + 2) : 0;  // clamp tail prefetch
        int4 iN = *(const int4*)(xrow + nb * 4);
        STEP(xg0, iA.z);
        STEP(xg1, iA.w);
        STEP(xg0, iB.x);
        STEP(xg1, iB.y);
        iA = iB; iB = iN;
    }
#undef STEP

    // ---- head: out[b] = 0.5 + 0.5*tanh(0.5*(h.W_cls + b_cls)) ----
    // Lane L==0 (j=0): hn=h_0, gather h_1..h_7 in R11's summation order.
    {
        float hs = swz_xor16(hn);               // h_4 at lane 0
        float v1 = dppf<DPP_QP1>(hn);
        float v2 = dppf<DPP_QP2>(hn);
        float v3 = dppf<DPP_QP3>(hn);
        float v5 = dppf<DPP_QP1>(hs);
        float v6 = dppf<DPP_QP2>(hs);
        float v7 = dppf<DPP_QP3>(hs);
        if (L == 0) {
            float z = b_cls[0]
                + hn * W_cls[0] + v1 * W_cls[1] + v2 * W_cls[2] + v3 * W_cls[3]
                + hs * W_cls[4] + v5 * W_cls[5] + v6 * W_cls[6] + v7 * W_cls[7];
            out[b] = __builtin_fmaf(0.5f, tanh_fast(0.5f * z), 0.5f);
        }
    }
}

extern "C" void kernel_launch(void* const* d_in, const int* in_sizes, int n_in,
                              void* d_out, int out_size, void* d_ws, size_t ws_size,
                              hipStream_t stream)
{
    (void)in_sizes; (void)n_in; (void)d_ws; (void)ws_size; (void)out_size;
    const int*   x     = (const int*)  d_in[0];
    const float* emb   = (const float*)d_in[1];
    const float* W_ih  = (const float*)d_in[2];
    const float* W_hh  = (const float*)d_in[3];
    const float* b_ih  = (const float*)d_in[4];
    const float* b_hh  = (const float*)d_in[5];
    const float* W_cls = (const float*)d_in[6];
    const float* b_cls = (const float*)d_in[7];
    float* out = (float*)d_out;

    const int lds_bytes = NV * 32 * 4;  // 128000 <= 163840 (gfx950 opt-in)
    hipFuncSetAttribute((const void*)lstm_fused,
                        hipFuncAttributeMaxDynamicSharedMemorySize, lds_bytes);

    lstm_fused<<<dim3(256), dim3(512), lds_bytes, stream>>>(
        x, emb, W_ih, W_hh, b_ih, b_hh, W_cls, b_cls, out);
}

// Round 2
// 290.633 us; speedup vs baseline: 1.3212x; 1.3212x over previous
//
#include <hip/hip_runtime.h>

#define TT 2048
#define NV 1000
#define LOG2E 1.4426950408889634f

typedef float f32x2 __attribute__((ext_vector_type(2)));

// ---- XLA/Eigen rational tanh — epilogue head only (off critical path).
__device__ __forceinline__ float tanh_fast(float x) {
    const float L = 7.90531110763549805f;
    x = __builtin_amdgcn_fmed3f(x, -L, L);
    float x2 = x * x;
    float p = -2.76076847742355e-16f;
    p = __builtin_fmaf(p, x2, 2.00018790482477e-13f);
    p = __builtin_fmaf(p, x2, -8.60467152213735e-11f);
    p = __builtin_fmaf(p, x2, 5.12229709037114e-08f);
    p = __builtin_fmaf(p, x2, 1.48572235717979e-05f);
    p = __builtin_fmaf(p, x2, 6.37261928875436e-04f);
    p = __builtin_fmaf(p, x2, 4.89352455891786e-03f);
    float q = 1.19825839466702e-06f;
    q = __builtin_fmaf(q, x2, 1.18534705686654e-04f);
    q = __builtin_fmaf(q, x2, 2.26843463243900e-03f);
    q = __builtin_fmaf(q, x2, 4.89352518554385e-03f);
    float r = __builtin_amdgcn_rcpf(q);
    return (x * p) * r;
}

// DPP cross-lane.
template <int CTRL>
__device__ __forceinline__ float dppf(float x) {
    return __int_as_float(__builtin_amdgcn_update_dpp(
        0, __float_as_int(x), CTRL, 0xF, 0xF, true));
}
#define DPP_XOR1 0xB1   // quad_perm [1,0,3,2]
#define DPP_XOR2 0x4E   // quad_perm [2,3,0,1]
#define DPP_XOR3 0x1B   // quad_perm [3,2,1,0]
#define DPP_ROR4 0x124  // row_ror:4 == xor4 on period-8 data (validated R3-R10)
#define DPP_HMIR 0x141  // row_half_mirror == xor7 within 8-lane half
#define DPP_ROR8 0x128  // row_ror:8 == xor8 within 16-row

// pk helpers: per-component ops are bitwise-identical to the scalar forms.
__device__ __forceinline__ f32x2 pkfma(f32x2 a, float b, f32x2 c) {
    return __builtin_elementwise_fma(a, (f32x2){b, b}, c);
}

// R13: revert to the validated R11 16-lane layout (245 us, absmax 0.0).
// SINGLE CHANGE vs R11: the dot product's lo/hi gate slots are packed into
// f32x2 so the compiler emits full-rate v_pk_fma_f32 / v_pk_mul_f32 /
// v_pk_add_f32 (VOP3P, gfx90a+). Per step: 16 fma + 2 mul + 2 add ->
// 8 pk_fma + 1 pk_mul + 1 pk_add (-10 issue slots). Per-component operation
// order is unchanged -> bitwise-identical numerics.
//   lo slot: s=0 -> i (sigma, e-form, prescale -log2e; n=1)
//            s=1 -> g (tanh, e-form, prescale -2log2e; n=1-e)
//   hi slot: f/o sigma via rcp(1+exp2(-log2e*pre)) (R6-validated, unchanged).
extern "C" __global__ void __launch_bounds__(256, 1)
lstm_fused(const int* __restrict__ x, const float* __restrict__ emb,
           const float* __restrict__ W_ih, const float* __restrict__ W_hh,
           const float* __restrict__ b_ih, const float* __restrict__ b_hh,
           const float* __restrict__ W_cls, const float* __restrict__ b_cls,
           float* __restrict__ out)
{
    extern __shared__ float TAB[];  // [1000][16] float2 rows, stride 128 B

    const int tid = threadIdx.x;
    const int l   = tid & 15;
    const int s   = l >> 3;
    const int j   = l & 7;
    const int grp = tid >> 4;

    const int glo = j + (s << 4);          // i_j (s0) or g_j (s1)
    const int ghi = glo + 8;               // f_j (s0) or o_j (s1)
    const float scx = s ? (-2.0f * LOG2E) : -LOG2E;  // lo-slot prescale
    const float scy = -LOG2E;                        // hi-slot sigma prescale
    const float kL  = s ? 1.0f : 0.0f;     // lo numerator: n = 1 - kL*e
    const bool is0 = (s == 0);

    // ---- phase 1: build TAB ----
    {
        float wl[8], wh[8];
        #pragma unroll
        for (int k = 0; k < 8; ++k) {
            wl[k] = W_ih[glo * 8 + k];
            wh[k] = W_ih[ghi * 8 + k];
        }
        const float bl = b_ih[glo] + b_hh[glo];
        const float bh = b_ih[ghi] + b_hh[ghi];
        for (int v = grp; v < NV; v += 16) {
            const float4 e0 = *(const float4*)(emb + v * 8);
            const float4 e1 = *(const float4*)(emb + v * 8 + 4);
            float dl = bl + e0.x*wl[0] + e0.y*wl[1] + e0.z*wl[2] + e0.w*wl[3]
                          + e1.x*wl[4] + e1.y*wl[5] + e1.z*wl[6] + e1.w*wl[7];
            float dh = bh + e0.x*wh[0] + e0.y*wh[1] + e0.z*wh[2] + e0.w*wh[3]
                          + e1.x*wh[4] + e1.y*wh[5] + e1.z*wh[6] + e1.w*wh[7];
            *(float2*)(TAB + v * 32 + l * 2) = make_float2(scx * dl, scy * dh);
        }
    }
    __syncthreads();

    // ---- recurrence ----
    const int b = blockIdx.x * 16 + grp;
    const int* __restrict__ xrow = x + (size_t)b * TT;
    const char* __restrict__ TABl = (const char*)TAB + l * 8;  // lane base

    // xor-ordered W_hh packed {lo,hi} (pairs with m_k = h_{j^m}; R3-R10 exact)
    f32x2 wpk[8];
    #pragma unroll
    for (int m = 0; m < 8; ++m) {
        wpk[m].x = scx * W_hh[glo * 8 + (j ^ m)];
        wpk[m].y = scy * W_hh[ghi * 8 + (j ^ m)];
    }

    float c  = 0.0f;
    float hn = 0.0f;   // lane l: h_{l&7} (period-8 within 16-row)

    int4 iA = *(const int4*)(xrow);
    int4 iB = *(const int4*)(xrow + 4);
    f32x2 xg0 = *(const f32x2*)(TABl + (iA.x << 7));  // depth-2 prefetch
    f32x2 xg1 = *(const f32x2*)(TABl + (iA.y << 7));

    // Dot chain order per component == R11: uA: m0,m2,m4,m6; uB: m1,m3,m5,m7.
#define STEP(XG, NIDX) do {                                                      \
        float mm  = dppf<DPP_HMIR>(hn);          /* m7, multi-use */             \
        f32x2 uA = pkfma(wpk[0], hn, XG);                                        \
        f32x2 uB = wpk[1] * (f32x2){dppf<DPP_XOR1>(hn), dppf<DPP_XOR1>(hn)};     \
        uA = pkfma(wpk[2], dppf<DPP_XOR2>(hn), uA);                              \
        uB = pkfma(wpk[3], dppf<DPP_XOR3>(hn), uB);                              \
        uA = pkfma(wpk[4], dppf<DPP_XOR3>(mm), uA);                              \
        uB = pkfma(wpk[5], dppf<DPP_XOR2>(mm), uB);                              \
        uA = pkfma(wpk[6], dppf<DPP_XOR1>(mm), uA);                              \
        uB = pkfma(wpk[7], mm, uB);                                              \
        f32x2 u = uA + uB;  /* .x: s0 -log2e*pre_i / s1 -2log2e*pre_g */         \
        XG = *(const f32x2*)(TABl + ((NIDX) << 7));   /* prefetch t+2 */         \
        float el = __builtin_amdgcn_exp2f(fminf(u.x, 126.0f));                   \
        float ey = __builtin_amdgcn_exp2f(u.y);                                  \
        float nl = __builtin_fmaf(-kL, el, 1.0f);  /* s0: 1; s1: 1-el */         \
        float aL = nl * __builtin_amdgcn_rcpf(1.0f + el);  /* sig(i)/tanh(g) */  \
        float sy = __builtin_amdgcn_rcpf(1.0f + ey);       /* sig(f)/sig(o) */   \
        float IG  = dppf<DPP_ROR8>(aL) * aL;      /* sig(i)*tanh(g), both */     \
        float pHi = dppf<DPP_ROR8>(sy);                                          \
        float F   = is0 ? sy : pHi;     /* sig(f) */                             \
        float O   = is0 ? pHi : sy;     /* sig(o) */                             \
        c  = __builtin_fmaf(F, c, IG);                                           \
        float uc = fminf(c * (-2.0f * LOG2E), 126.0f);                           \
        float ec = __builtin_amdgcn_exp2f(uc);                                   \
        float tc = (1.0f - ec) * __builtin_amdgcn_rcpf(1.0f + ec);               \
        hn = O * tc;                                                             \
    } while (0)

    for (int t = 0; t < TT; t += 4) {
        const int nb = (t + 8 < TT) ? (t / 4 + 2) : 0;  // clamp tail prefetch
        int4 iN = *(const int4*)(xrow + nb * 4);
        STEP(xg0, iA.z);
        STEP(xg1, iA.w);
        STEP(xg0, iB.x);
        STEP(xg1, iB.y);
        iA = iB; iB = iN;
    }
#undef STEP

    // ---- head: out[b] = 0.5 + 0.5*tanh(0.5*(h.W_cls + b_cls)) ----
    // Lane l==0: hn=h_0, v_m=h_m -> same summation order as R2-R11.
    {
        float v1 = dppf<DPP_XOR1>(hn);
        float v2 = dppf<DPP_XOR2>(hn);
        float v3 = dppf<DPP_XOR3>(hn);
        float v4 = dppf<DPP_ROR4>(hn);
        float v5 = dppf<DPP_XOR1>(v4);
        float v6 = dppf<DPP_XOR2>(v4);
        float v7 = dppf<DPP_XOR3>(v4);
        if (l == 0) {
            float z = b_cls[0]
                + hn * W_cls[0] + v1 * W_cls[1] + v2 * W_cls[2] + v3 * W_cls[3]
                + v4 * W_cls[4] + v5 * W_cls[5] + v6 * W_cls[6] + v7 * W_cls[7];
            out[b] = __builtin_fmaf(0.5f, tanh_fast(0.5f * z), 0.5f);
        }
    }
}

extern "C" void kernel_launch(void* const* d_in, const int* in_sizes, int n_in,
                              void* d_out, int out_size, void* d_ws, size_t ws_size,
                              hipStream_t stream)
{
    (void)in_sizes; (void)n_in; (void)d_ws; (void)ws_size; (void)out_size;
    const int*   x     = (const int*)  d_in[0];
    const float* emb   = (const float*)d_in[1];
    const float* W_ih  = (const float*)d_in[2];
    const float* W_hh  = (const float*)d_in[3];
    const float* b_ih  = (const float*)d_in[4];
    const float* b_hh  = (const float*)d_in[5];
    const float* W_cls = (const float*)d_in[6];
    const float* b_cls = (const float*)d_in[7];
    float* out = (float*)d_out;

    const int lds_bytes = NV * 16 * 8;  // 128000 <= 163840 (gfx950 opt-in)
    hipFuncSetAttribute((const void*)lstm_fused,
                        hipFuncAttributeMaxDynamicSharedMemorySize, lds_bytes);

    lstm_fused<<<dim3(256), dim3(256), lds_bytes, stream>>>(
        x, emb, W_ih, W_hh, b_ih, b_hh, W_cls, b_cls, out);
}

// Round 4
// 275.646 us; speedup vs baseline: 1.3930x; 1.0544x over previous
//
#include <hip/hip_runtime.h>

#define TT 2048
#define NV 1000
#define LOG2E 1.4426950408889634f

typedef float f32x2 __attribute__((ext_vector_type(2)));

// ---- XLA/Eigen rational tanh — epilogue head only (off critical path).
__device__ __forceinline__ float tanh_fast(float x) {
    const float L = 7.90531110763549805f;
    x = __builtin_amdgcn_fmed3f(x, -L, L);
    float x2 = x * x;
    float p = -2.76076847742355e-16f;
    p = __builtin_fmaf(p, x2, 2.00018790482477e-13f);
    p = __builtin_fmaf(p, x2, -8.60467152213735e-11f);
    p = __builtin_fmaf(p, x2, 5.12229709037114e-08f);
    p = __builtin_fmaf(p, x2, 1.48572235717979e-05f);
    p = __builtin_fmaf(p, x2, 6.37261928875436e-04f);
    p = __builtin_fmaf(p, x2, 4.89352455891786e-03f);
    float q = 1.19825839466702e-06f;
    q = __builtin_fmaf(q, x2, 1.18534705686654e-04f);
    q = __builtin_fmaf(q, x2, 2.26843463243900e-03f);
    q = __builtin_fmaf(q, x2, 4.89352518554385e-03f);
    float r = __builtin_amdgcn_rcpf(q);
    return (x * p) * r;
}

// DPP cross-lane.
template <int CTRL>
__device__ __forceinline__ float dppf(float x) {
    return __int_as_float(__builtin_amdgcn_update_dpp(
        0, __float_as_int(x), CTRL, 0xF, 0xF, true));
}
#define DPP_XOR1 0xB1   // quad_perm [1,0,3,2]
#define DPP_XOR2 0x4E   // quad_perm [2,3,0,1]
#define DPP_XOR3 0x1B   // quad_perm [3,2,1,0]
#define DPP_ROR4 0x124  // row_ror:4 == xor4 on period-8 data (validated R3-R10)
#define DPP_HMIR 0x141  // row_half_mirror == xor7 within 8-lane half
#define DPP_ROR8 0x128  // row_ror:8 == xor8 within 16-row

// pk helpers: per-component ops are bitwise-identical to the scalar forms.
__device__ __forceinline__ f32x2 pkfma(f32x2 a, float b, f32x2 c) {
    return __builtin_elementwise_fma(a, (f32x2){b, b}, c);
}

// R14 (re-run; previous attempt died to container infra, no data).
// Chain surgery on the validated R13 kernel (236.5 us best, absmax 0.0).
// The step is critical-path-latency-bound (~277 cyc vs ~194 busy). Changes
// shorten the serial chain through the 4 on-chain transcendentals:
//  (1) tanh via fma(2,r,-1) form: removes both fminf clamps + nl/sub ops.
//      Inf-safe: rcp(inf)=0 -> tanh=+/-1 exactly. Sigma slot: fma(1,r,0)=r,
//      bitwise identical to R13.
//  (2) c tracked in scaled domain cs = -2log2e*c; the scale is folded into
//      the tanh(g) fma constants, so exp2(cs) needs no mul+min on the chain.
//  (3) hn = fma(2O, rc, -O): 2O computed off-chain during the c-exp.
// All deltas are the ~1-ulp exp/rcp error class validated absmax-0.0 R6-R13.
extern "C" __global__ void __launch_bounds__(256, 1)
lstm_fused(const int* __restrict__ x, const float* __restrict__ emb,
           const float* __restrict__ W_ih, const float* __restrict__ W_hh,
           const float* __restrict__ b_ih, const float* __restrict__ b_hh,
           const float* __restrict__ W_cls, const float* __restrict__ b_cls,
           float* __restrict__ out)
{
    extern __shared__ float TAB[];  // [1000][16] float2 rows, stride 128 B

    const int tid = threadIdx.x;
    const int l   = tid & 15;
    const int s   = l >> 3;
    const int j   = l & 7;
    const int grp = tid >> 4;

    const int glo = j + (s << 4);          // i_j (s0) or g_j (s1)
    const int ghi = glo + 8;               // f_j (s0) or o_j (s1)
    const float scx = s ? (-2.0f * LOG2E) : -LOG2E;  // lo-slot prescale
    const float scy = -LOG2E;                        // hi-slot sigma prescale
    // aLk = fma(Ax, r, Bx):  s0 -> sigma(i) = r (exact: fma(1,r,0))
    //                        s1 -> k*tanh(g) = fma(2k, r, -k), k = -2log2e
    const float Ax = s ? (-4.0f * LOG2E) : 1.0f;
    const float Bx = s ? ( 2.0f * LOG2E) : 0.0f;
    const bool is0 = (s == 0);

    // ---- phase 1: build TAB ----
    {
        float wl[8], wh[8];
        #pragma unroll
        for (int k = 0; k < 8; ++k) {
            wl[k] = W_ih[glo * 8 + k];
            wh[k] = W_ih[ghi * 8 + k];
        }
        const float bl = b_ih[glo] + b_hh[glo];
        const float bh = b_ih[ghi] + b_hh[ghi];
        for (int v = grp; v < NV; v += 16) {
            const float4 e0 = *(const float4*)(emb + v * 8);
            const float4 e1 = *(const float4*)(emb + v * 8 + 4);
            float dl = bl + e0.x*wl[0] + e0.y*wl[1] + e0.z*wl[2] + e0.w*wl[3]
                          + e1.x*wl[4] + e1.y*wl[5] + e1.z*wl[6] + e1.w*wl[7];
            float dh = bh + e0.x*wh[0] + e0.y*wh[1] + e0.z*wh[2] + e0.w*wh[3]
                          + e1.x*wh[4] + e1.y*wh[5] + e1.z*wh[6] + e1.w*wh[7];
            *(float2*)(TAB + v * 32 + l * 2) = make_float2(scx * dl, scy * dh);
        }
    }
    __syncthreads();

    // ---- recurrence ----
    const int b = blockIdx.x * 16 + grp;
    const int* __restrict__ xrow = x + (size_t)b * TT;
    const char* __restrict__ TABl = (const char*)TAB + l * 8;  // lane base

    // xor-ordered W_hh packed {lo,hi} (pairs with m_k = h_{j^m}; R3-R13 exact)
    f32x2 wpk[8];
    #pragma unroll
    for (int m = 0; m < 8; ++m) {
        wpk[m].x = scx * W_hh[glo * 8 + (j ^ m)];
        wpk[m].y = scy * W_hh[ghi * 8 + (j ^ m)];
    }

    float cs = 0.0f;   // scaled cell state: cs = -2log2e * c
    float hn = 0.0f;   // lane l: h_{l&7} (period-8 within 16-row)

    int4 iA = *(const int4*)(xrow);
    int4 iB = *(const int4*)(xrow + 4);
    f32x2 xg0 = *(const f32x2*)(TABl + (iA.x << 7));  // depth-2 prefetch
    f32x2 xg1 = *(const f32x2*)(TABl + (iA.y << 7));

    // Dot chain order per component == R6/R9/R13: uA: m0,m2,m4,m6; uB: m1..m7.
#define STEP(XG, NIDX) do {                                                      \
        float mm  = dppf<DPP_HMIR>(hn);          /* m7, multi-use */             \
        f32x2 uA = pkfma(wpk[0], hn, XG);                                        \
        f32x2 uB = wpk[1] * (f32x2){dppf<DPP_XOR1>(hn), dppf<DPP_XOR1>(hn)};     \
        uA = pkfma(wpk[2], dppf<DPP_XOR2>(hn), uA);                              \
        uB = pkfma(wpk[3], dppf<DPP_XOR3>(hn), uB);                              \
        uA = pkfma(wpk[4], dppf<DPP_XOR3>(mm), uA);                              \
        uB = pkfma(wpk[5], dppf<DPP_XOR2>(mm), uB);                              \
        uA = pkfma(wpk[6], dppf<DPP_XOR1>(mm), uA);                              \
        uB = pkfma(wpk[7], mm, uB);                                              \
        f32x2 u = uA + uB;  /* .x: s0 -log2e*pre_i / s1 -2log2e*pre_g */         \
        XG = *(const f32x2*)(TABl + ((NIDX) << 7));   /* prefetch t+2 */         \
        float el = __builtin_amdgcn_exp2f(u.x);                                  \
        float ey = __builtin_amdgcn_exp2f(u.y);                                  \
        float r  = __builtin_amdgcn_rcpf(1.0f + el);                             \
        float aLk = __builtin_fmaf(Ax, r, Bx);   /* sig(i) / k*tanh(g) */        \
        float sy = __builtin_amdgcn_rcpf(1.0f + ey);  /* sig(f)/sig(o) */        \
        float IG  = dppf<DPP_ROR8>(aLk) * aLk;   /* k*sig(i)*tanh(g), both */    \
        float pHi = dppf<DPP_ROR8>(sy);                                          \
        float F   = is0 ? sy : pHi;     /* sig(f) */                             \
        float O   = is0 ? pHi : sy;     /* sig(o) */                             \
        float twoO = O + O;                                                      \
        cs = __builtin_fmaf(F, cs, IG);          /* cs = k*c */                  \
        float ec = __builtin_amdgcn_exp2f(cs);   /* e^{-2c}, inf-safe */         \
        float rc = __builtin_amdgcn_rcpf(1.0f + ec);                             \
        hn = __builtin_fmaf(twoO, rc, -O);       /* O * tanh(c) */               \
    } while (0)

    for (int t = 0; t < TT; t += 4) {
        const int nb = (t + 8 < TT) ? (t / 4 + 2) : 0;  // clamp tail prefetch
        int4 iN = *(const int4*)(xrow + nb * 4);
        STEP(xg0, iA.z);
        STEP(xg1, iA.w);
        STEP(xg0, iB.x);
        STEP(xg1, iB.y);
        iA = iB; iB = iN;
    }
#undef STEP

    // ---- head: out[b] = 0.5 + 0.5*tanh(0.5*(h.W_cls + b_cls)) ----
    // Lane l==0: hn=h_0, v_m=h_m -> same summation order as R2-R13.
    {
        float v1 = dppf<DPP_XOR1>(hn);
        float v2 = dppf<DPP_XOR2>(hn);
        float v3 = dppf<DPP_XOR3>(hn);
        float v4 = dppf<DPP_ROR4>(hn);
        float v5 = dppf<DPP_XOR1>(v4);
        float v6 = dppf<DPP_XOR2>(v4);
        float v7 = dppf<DPP_XOR3>(v4);
        if (l == 0) {
            float z = b_cls[0]
                + hn * W_cls[0] + v1 * W_cls[1] + v2 * W_cls[2] + v3 * W_cls[3]
                + v4 * W_cls[4] + v5 * W_cls[5] + v6 * W_cls[6] + v7 * W_cls[7];
            out[b] = __builtin_fmaf(0.5f, tanh_fast(0.5f * z), 0.5f);
        }
    }
}

extern "C" void kernel_launch(void* const* d_in, const int* in_sizes, int n_in,
                              void* d_out, int out_size, void* d_ws, size_t ws_size,
                              hipStream_t stream)
{
    (void)in_sizes; (void)n_in; (void)d_ws; (void)ws_size; (void)out_size;
    const int*   x     = (const int*)  d_in[0];
    const float* emb   = (const float*)d_in[1];
    const float* W_ih  = (const float*)d_in[2];
    const float* W_hh  = (const float*)d_in[3];
    const float* b_ih  = (const float*)d_in[4];
    const float* b_hh  = (const float*)d_in[5];
    const float* W_cls = (const float*)d_in[6];
    const float* b_cls = (const float*)d_in[7];
    float* out = (float*)d_out;

    const int lds_bytes = NV * 16 * 8;  // 128000 <= 163840 (gfx950 opt-in)
    hipFuncSetAttribute((const void*)lstm_fused,
                        hipFuncAttributeMaxDynamicSharedMemorySize, lds_bytes);

    lstm_fused<<<dim3(256), dim3(256), lds_bytes, stream>>>(
        x, emb, W_ih, W_hh, b_ih, b_hh, W_cls, b_cls, out);
}